// Round 9
// baseline (717.658 us; speedup 1.0000x reference)
//
#include <hip/hip_runtime.h>
#include <math.h>

#define B_ROWS 32768
#define K_CODES 4096
#define D_DIM 128
#define MARGIN 1.5e-3f
#define CAP 64

typedef short bf16x8 __attribute__((ext_vector_type(8)));
typedef float f32x4 __attribute__((ext_vector_type(4)));

// RNE float->bf16 (finite inputs only)
__device__ __forceinline__ unsigned short f2bf(float f) {
  union { float f; unsigned int u; } v; v.f = f;
  unsigned int r = (v.u + 0x7FFFu + ((v.u >> 16) & 1u)) >> 16;
  return (unsigned short)r;
}

// order-preserving float<->uint mapping
__device__ __forceinline__ unsigned fmap(float f) {
  unsigned u = __float_as_uint(f);
  return (u & 0x80000000u) ? ~u : (u | 0x80000000u);
}
__device__ __forceinline__ float funmap(unsigned k) {
  unsigned u = (k & 0x80000000u) ? (k ^ 0x80000000u) : ~k;
  return __uint_as_float(u);
}

// Row sum-of-squares, numpy pairwise order (validated): loads batched FIRST
// (no asm between loads!), then the asm-guarded VALU chain on registers.
// 8 lanes/row: lane j sums fl(v_{8i+j}^2) ascending i, shfl-xor 1,2,4 combine.
__device__ __forceinline__ float row_sq8(const float* __restrict__ src, int lane) {
  float vals[16];
#pragma unroll
  for (int i = 0; i < 16; ++i) vals[i] = src[i * 8 + lane];  // batched loads
  float t = vals[0] * vals[0];
  asm volatile("" : "+v"(t));  // keep fl(v*v) un-fused (VALU-only barrier now)
  float acc = t;
#pragma unroll
  for (int i = 1; i < 16; ++i) {
    float tt = vals[i] * vals[i];
    asm volatile("" : "+v"(tt));
    acc = acc + tt;
  }
  acc = acc + __shfl_xor(acc, 1, 64);
  acc = acc + __shfl_xor(acc, 2, 64);
  acc = acc + __shfl_xor(acc, 4, 64);
  return acc;  // all 8 lanes of the group hold the row sum
}

// ---------------------------------------------------------------------------
// Kernel 1: prep — x2 (all rows), e2, and eb bf16 cast packed in MFMA-fragment
// order: eb[((ch*8+nt)*4+ks)*64 + lane]*8 shorts (lane-contiguous dwordx4).
// ---------------------------------------------------------------------------
__global__ __launch_bounds__(256) void prep(const float* __restrict__ x,
                                            const float* __restrict__ emb,
                                            float* __restrict__ x2,
                                            float* __restrict__ e2,
                                            unsigned short* __restrict__ eb) {
  const int t0 = blockIdx.x * 256 + threadIdx.x;
  const int stride = gridDim.x * 256;
  for (int s = t0; s < B_ROWS * 8; s += stride) {
    int row = s >> 3, lane = s & 7;
    float acc = row_sq8(x + (size_t)row * D_DIM, lane);
    if (lane == 0) x2[row] = acc;
  }
  for (int s = t0; s < K_CODES * 8; s += stride) {
    int row = s >> 3, lane = s & 7;
    float acc = row_sq8(emb + (size_t)row * D_DIM, lane);
    if (lane == 0) e2[row] = acc;
  }
  for (int g = t0; g < K_CODES * 4; g += stride) {
    int c = g >> 2, ks = g & 3;
    int ch = c >> 7, nt = (c >> 4) & 7, lr = c & 15;
    const float4* src = (const float4*)(emb + (size_t)c * D_DIM + ks * 32);
    unsigned short* dst = eb + ((size_t)((ch * 8 + nt) * 4 + ks) * 64 + lr) * 8;
#pragma unroll
    for (int qq = 0; qq < 4; ++qq) {
      float4 v0 = src[qq * 2];
      float4 v1 = src[qq * 2 + 1];
      ushort4 o0 = make_ushort4(f2bf(v0.x), f2bf(v0.y), f2bf(v0.z), f2bf(v0.w));
      ushort4 o1 = make_ushort4(f2bf(v1.x), f2bf(v1.y), f2bf(v1.z), f2bf(v1.w));
      *(ushort4*)(dst + qq * 128) = o0;
      *(ushort4*)(dst + qq * 128 + 4) = o1;
    }
  }
}

// ---------------------------------------------------------------------------
// Kernel 2: sweep — SINGLE MFMA pass: running-bound candidate collection
// (round-6 validated logic in round-8 validated layout).  256 thr (4 waves),
// 32 rows/block, 1024 blocks.  Wave wid covers n-tiles wid*2..wid*2+1.
// Chunk 0 calibrates per-row bound; chunks 1..31 append (col,t) when
// t <= rm+M (rm = thread-local running min, merged into LDS RMM via
// atomicMin every 4 chunks).  Bound >= final_min+M always -> superset of all
// exact winners (MARGIN bound validated rounds 4-8).  Final RMM = exact
// global approx min (all lanes merged at ch=31).
// ---------------------------------------------------------------------------
__global__ __launch_bounds__(256, 3) void sweep(
    const float* __restrict__ x, const unsigned short* __restrict__ eb,
    const float* __restrict__ e2g, unsigned int* __restrict__ RMMg,
    unsigned int* __restrict__ cntg, unsigned short* __restrict__ listsg,
    float* __restrict__ tvalsg) {
  __shared__ float m2[32 * 4];
  __shared__ unsigned RMM[32];
  __shared__ unsigned cnt[32];
  __shared__ unsigned short lists[32 * CAP];
  __shared__ float tvals[32 * CAP];

  const int tid = threadIdx.x;
  const int wid = tid >> 6, lane = tid & 63;
  const int q = lane >> 4, lr = lane & 15;
  const int rowbase = blockIdx.x * 32;

  bf16x8 af[2][4];
#pragma unroll
  for (int mi = 0; mi < 2; ++mi) {
    const float* xr = x + (size_t)(rowbase + mi * 16 + lr) * D_DIM;
#pragma unroll
    for (int ks = 0; ks < 4; ++ks) {
      float4 v0 = *(const float4*)(xr + ks * 32 + q * 8);
      float4 v1 = *(const float4*)(xr + ks * 32 + q * 8 + 4);
      bf16x8 f;
      f[0] = (short)f2bf(v0.x); f[1] = (short)f2bf(v0.y);
      f[2] = (short)f2bf(v0.z); f[3] = (short)f2bf(v0.w);
      f[4] = (short)f2bf(v1.x); f[5] = (short)f2bf(v1.y);
      f[6] = (short)f2bf(v1.z); f[7] = (short)f2bf(v1.w);
      af[mi][ks] = f;
    }
  }
  if (tid < 32) cnt[tid] = 0;

  // ---- chunk 0: calibrate per-row bound ----
  float t0v[2][2][4];
  {
    bf16x8 bf[2][4];
    float ev[2];
#pragma unroll
    for (int ni = 0; ni < 2; ++ni) {
      int nt = wid * 2 + ni;
#pragma unroll
      for (int ks = 0; ks < 4; ++ks)
        bf[ni][ks] = *(const bf16x8*)(eb + ((size_t)(nt * 4 + ks) * 64 + lane) * 8);
      ev[ni] = e2g[nt * 16 + lr];
    }
    f32x4 acc[2][2];
#pragma unroll
    for (int mi = 0; mi < 2; ++mi)
#pragma unroll
      for (int ni = 0; ni < 2; ++ni) { f32x4 z = {0.f, 0.f, 0.f, 0.f}; acc[mi][ni] = z; }
#pragma unroll
    for (int ks = 0; ks < 4; ++ks)
#pragma unroll
      for (int mi = 0; mi < 2; ++mi)
#pragma unroll
        for (int ni = 0; ni < 2; ++ni)
          acc[mi][ni] = __builtin_amdgcn_mfma_f32_16x16x32_bf16(
              af[mi][ks], bf[ni][ks], acc[mi][ni], 0, 0, 0);
#pragma unroll
    for (int mi = 0; mi < 2; ++mi)
#pragma unroll
      for (int ni = 0; ni < 2; ++ni)
#pragma unroll
        for (int rg = 0; rg < 4; ++rg)
          t0v[mi][ni][rg] = __builtin_fmaf(-2.0f, acc[mi][ni][rg], ev[ni]);
  }
  // per-slot min over ni, cross-lane reduce, merge into RMM
#pragma unroll
  for (int sl = 0; sl < 8; ++sl) {
    int mi = sl >> 2, rg = sl & 3;
    float v = fminf(t0v[mi][0][rg], t0v[mi][1][rg]);
    v = fminf(v, __shfl_xor(v, 1, 64));
    v = fminf(v, __shfl_xor(v, 2, 64));
    v = fminf(v, __shfl_xor(v, 4, 64));
    v = fminf(v, __shfl_xor(v, 8, 64));
    if (lr == 0) m2[(mi * 16 + q * 4 + rg) * 4 + wid] = v;
  }
  __syncthreads();
  if (tid < 32) {
    float a = fminf(m2[tid * 4], m2[tid * 4 + 1]);
    float b = fminf(m2[tid * 4 + 2], m2[tid * 4 + 3]);
    RMM[tid] = fmap(fminf(a, b));
  }
  __syncthreads();

  float rm[8];
#pragma unroll
  for (int sl = 0; sl < 8; ++sl)
    rm[sl] = funmap(RMM[(sl >> 2) * 16 + q * 4 + (sl & 3)]);

  // append chunk-0 survivors
#pragma unroll
  for (int mi = 0; mi < 2; ++mi)
#pragma unroll
    for (int ni = 0; ni < 2; ++ni) {
      int colc = (wid * 2 + ni) * 16 + lr;
#pragma unroll
      for (int rg = 0; rg < 4; ++rg) {
        float t = t0v[mi][ni][rg];
        if (t <= rm[mi * 4 + rg] + MARGIN) {
          int row = mi * 16 + q * 4 + rg;
          unsigned p = atomicAdd(&cnt[row], 1u);
          if (p < CAP) { lists[row * CAP + p] = (unsigned short)colc; tvals[row * CAP + p] = t; }
        }
      }
    }

  // ---- chunks 1..31: stream with running bound ----
#pragma unroll 1
  for (int ch = 1; ch < 32; ++ch) {
    bf16x8 bf[2][4];
    float ev[2];
#pragma unroll
    for (int ni = 0; ni < 2; ++ni) {
      int nt = wid * 2 + ni;
#pragma unroll
      for (int ks = 0; ks < 4; ++ks)
        bf[ni][ks] = *(const bf16x8*)(eb + ((size_t)((ch * 8 + nt) * 4 + ks) * 64 + lane) * 8);
      ev[ni] = e2g[ch * 128 + nt * 16 + lr];
    }
    f32x4 acc[2][2];
#pragma unroll
    for (int mi = 0; mi < 2; ++mi)
#pragma unroll
      for (int ni = 0; ni < 2; ++ni) { f32x4 z = {0.f, 0.f, 0.f, 0.f}; acc[mi][ni] = z; }
#pragma unroll
    for (int ks = 0; ks < 4; ++ks)
#pragma unroll
      for (int mi = 0; mi < 2; ++mi)
#pragma unroll
        for (int ni = 0; ni < 2; ++ni)
          acc[mi][ni] = __builtin_amdgcn_mfma_f32_16x16x32_bf16(
              af[mi][ks], bf[ni][ks], acc[mi][ni], 0, 0, 0);
#pragma unroll
    for (int mi = 0; mi < 2; ++mi)
#pragma unroll
      for (int ni = 0; ni < 2; ++ni) {
        int colc = ch * 128 + (wid * 2 + ni) * 16 + lr;
#pragma unroll
        for (int rg = 0; rg < 4; ++rg) {
          float t = __builtin_fmaf(-2.0f, acc[mi][ni][rg], ev[ni]);
          int sl = mi * 4 + rg;
          if (t <= rm[sl] + MARGIN) {
            int row = mi * 16 + q * 4 + rg;
            unsigned p = atomicAdd(&cnt[row], 1u);
            if (p < CAP) { lists[row * CAP + p] = (unsigned short)colc; tvals[row * CAP + p] = t; }
          }
          rm[sl] = fminf(rm[sl], t);
        }
      }
    if ((ch & 3) == 3) {  // refresh shared bound (incl. final ch=31)
#pragma unroll
      for (int sl = 0; sl < 8; ++sl) {
        float v = rm[sl];
        v = fminf(v, __shfl_xor(v, 1, 64));
        v = fminf(v, __shfl_xor(v, 2, 64));
        v = fminf(v, __shfl_xor(v, 4, 64));
        v = fminf(v, __shfl_xor(v, 8, 64));
        rm[sl] = v;
      }
      if (lr == 0) {
#pragma unroll
        for (int sl = 0; sl < 8; ++sl)
          atomicMin(&RMM[(sl >> 2) * 16 + q * 4 + (sl & 3)], fmap(rm[sl]));
      }
#pragma unroll
      for (int sl = 0; sl < 8; ++sl)
        rm[sl] = fminf(rm[sl], funmap(RMM[(sl >> 2) * 16 + q * 4 + (sl & 3)]));
    }
  }
  __syncthreads();  // cnt, lists, tvals, RMM final

  if (tid < 32) {
    RMMg[rowbase + tid] = RMM[tid];   // exact global approx min (fmap'd)
    cntg[rowbase + tid] = cnt[tid];
  }
  for (int i = tid; i < 32 * CAP; i += 256) {
    listsg[(size_t)rowbase * CAP + i] = lists[i];
    tvalsg[(size_t)rowbase * CAP + i] = tvals[i];
  }
}

// ---------------------------------------------------------------------------
// Kernel 3: rescore v3 — LDS-staged x rows, final-min filter, exact fp32
// chain (bit-validated), lexicographic (s,col) reduction.  32 rows/block,
// 8 lanes/row, 1024 blocks.  No per-thread x2 (reads precomputed x2g).
// ---------------------------------------------------------------------------
__global__ __launch_bounds__(256) void rescore(
    const float* __restrict__ x, const float* __restrict__ emb,
    const float* __restrict__ x2g, const float* __restrict__ e2g,
    const unsigned int* __restrict__ RMMg, const unsigned int* __restrict__ cntg,
    const unsigned short* __restrict__ listsg, const float* __restrict__ tvalsg,
    float* __restrict__ out_idx, unsigned int* __restrict__ counts) {
  __shared__ float xf[32 * 132];  // padded stride vs bank alias
  __shared__ int nofl;
  __shared__ int oflrows[32];
  __shared__ float redv[256];
  __shared__ int redi[256];
  const int tid = threadIdx.x;
  const int rl = tid >> 3;   // row within block
  const int j = tid & 7;     // lane within row-group
  const int rowbase = blockIdx.x * 32;
  const int r = rowbase + rl;
  if (tid == 0) nofl = 0;

  {  // stage 32 x rows (coalesced float4)
    const float4* src = (const float4*)(x + (size_t)rowbase * D_DIM);
#pragma unroll
    for (int p = 0; p < 4; ++p) {
      int idx = p * 256 + tid;
      int rr = idx >> 5, cc = idx & 31;
      *(float4*)(xf + rr * 132 + cc * 4) = src[idx];
    }
  }
  __syncthreads();

  const float xs2 = x2g[r];
  const float* xr = xf + rl * 132;
  int c = (int)cntg[r];
  if (c <= CAP) {
    float mlim = funmap(RMMg[r]) + MARGIN;
    float best = 3.4e38f;
    int bidx = 0x7fffffff;
    for (int jj = j; jj < c; jj += 8) {
      float tv = tvalsg[(size_t)r * CAP + jj];
      if (tv > mlim) continue;                   // final-min filter
      int col = listsg[(size_t)r * CAP + jj];
      float dot = 0.f;
      const float4* ev = (const float4*)(emb + (size_t)col * D_DIM);
#pragma unroll 8
      for (int d4 = 0; d4 < 32; ++d4) {  // exact ascending-d fmaf chain
        float4 e4 = ev[d4];
        dot = __builtin_fmaf(xr[d4 * 4 + 0], e4.x, dot);
        dot = __builtin_fmaf(xr[d4 * 4 + 1], e4.y, dot);
        dot = __builtin_fmaf(xr[d4 * 4 + 2], e4.z, dot);
        dot = __builtin_fmaf(xr[d4 * 4 + 3], e4.w, dot);
      }
      float t1 = xs2 + e2g[col];                 // fl(x2+e2)
      float s = __builtin_fmaf(-2.0f, dot, t1);  // fl(t1 - 2*dot)
      if (s < best || (s == best && col < bidx)) { best = s; bidx = col; }
    }
#pragma unroll
    for (int m = 1; m <= 4; m <<= 1) {  // lexicographic (s,col) min, 8 lanes
      float ov = __shfl_xor(best, m, 64);
      int oi = __shfl_xor(bidx, m, 64);
      if (ov < best || (ov == best && oi < bidx)) { best = ov; bidx = oi; }
    }
    if (j == 0) {
      out_idx[r] = (float)bidx;
      atomicAdd(&counts[bidx], 1u);
    }
  } else if (j == 0) {
    int p = atomicAdd(&nofl, 1);
    oflrows[p] = rl;
  }
  __syncthreads();

  // cooperative exact full scan for overflow rows (expected never)
  for (int k = 0; k < nofl; ++k) {
    int rloc = oflrows[k];
    int rr = rowbase + rloc;
    const float* xrr = xf + rloc * 132;
    float xs2r = x2g[rr];
    float lbest = 3.4e38f;
    int lidx = 0x7fffffff;
    for (int c0 = tid; c0 < K_CODES; c0 += 256) {
      float dot = 0.f;
      const float4* ev = (const float4*)(emb + (size_t)c0 * D_DIM);
      for (int d4 = 0; d4 < 32; ++d4) {
        float4 e4 = ev[d4];
        dot = __builtin_fmaf(xrr[d4 * 4 + 0], e4.x, dot);
        dot = __builtin_fmaf(xrr[d4 * 4 + 1], e4.y, dot);
        dot = __builtin_fmaf(xrr[d4 * 4 + 2], e4.z, dot);
        dot = __builtin_fmaf(xrr[d4 * 4 + 3], e4.w, dot);
      }
      float s = __builtin_fmaf(-2.0f, dot, xs2r + e2g[c0]);
      if (s < lbest || (s == lbest && c0 < lidx)) { lbest = s; lidx = c0; }
    }
    redv[tid] = lbest;
    redi[tid] = lidx;
    __syncthreads();
    if (tid == 0) {
      float bv = redv[0]; int bi = redi[0];
      for (int t2 = 1; t2 < 256; ++t2) {
        float vv = redv[t2]; int i2 = redi[t2];
        if (vv < bv || (vv == bv && i2 < bi)) { bv = vv; bi = i2; }
      }
      out_idx[rr] = (float)bi;
      atomicAdd(&counts[bi], 1u);
    }
    __syncthreads();
  }
}

// ---------------------------------------------------------------------------
// Kernel 4 (round-2..8 validated): gather + straight-through + losses.
// ---------------------------------------------------------------------------
__global__ __launch_bounds__(256) void vq_gather(const float* __restrict__ x,
                                                 const float* __restrict__ emb,
                                                 const float* __restrict__ idxf,
                                                 float* __restrict__ out_q,
                                                 double* __restrict__ sums) {
  int r = blockIdx.x * 8 + (threadIdx.x >> 5);
  int lane = threadIdx.x & 31;
  int idx = (int)idxf[r];
  const float4 q = *(const float4*)(emb + (size_t)idx * 128 + lane * 4);
  const float4 xv = *(const float4*)(x + (size_t)r * 128 + lane * 4);
  float d0 = q.x - xv.x, d1 = q.y - xv.y, d2 = q.z - xv.z, d3 = q.w - xv.w;
  float s0 = xv.x + d0, s1 = xv.y + d1, s2 = xv.z + d2, s3 = xv.w + d3;
  *(float4*)(out_q + (size_t)r * 128 + lane * 4) = make_float4(s0, s1, s2, s3);
  float g0 = s0 - xv.x, g1 = s1 - xv.y, g2 = s2 - xv.z, g3 = s3 - xv.w;
  double es = (double)(d0 * d0) + (double)(d1 * d1) + (double)(d2 * d2) + (double)(d3 * d3);
  double qs = (double)(g0 * g0) + (double)(g1 * g1) + (double)(g2 * g2) + (double)(g3 * g3);
#pragma unroll
  for (int off = 32; off >= 1; off >>= 1) {
    es += __shfl_down(es, off, 64);
    qs += __shfl_down(qs, off, 64);
  }
  __shared__ double lred[2][4];
  int w = threadIdx.x >> 6;
  if ((threadIdx.x & 63) == 0) { lred[0][w] = es; lred[1][w] = qs; }
  __syncthreads();
  if (threadIdx.x == 0) {
    double e = lred[0][0] + lred[0][1] + lred[0][2] + lred[0][3];
    double qq = lred[1][0] + lred[1][1] + lred[1][2] + lred[1][3];
    atomicAdd(&sums[0], e);
    atomicAdd(&sums[1], qq);
  }
}

// ---------------------------------------------------------------------------
// Kernel 5 (validated): finalize scalars.
// ---------------------------------------------------------------------------
__global__ __launch_bounds__(256) void vq_final(const unsigned int* __restrict__ counts,
                                                const double* __restrict__ sums,
                                                float* __restrict__ out_scalars) {
  double s = 0.0;
  for (int k = threadIdx.x; k < K_CODES; k += 256) {
    float p = (float)counts[k] * (1.0f / 32768.0f);
    float term = p * logf(p + 1e-10f);
    s += (double)term;
  }
#pragma unroll
  for (int off = 32; off >= 1; off >>= 1) s += __shfl_down(s, off, 64);
  __shared__ double red[4];
  if ((threadIdx.x & 63) == 0) red[threadIdx.x >> 6] = s;
  __syncthreads();
  if (threadIdx.x == 0) {
    double tot = red[0] + red[1] + red[2] + red[3];
    float e_lat = (float)(sums[0] / (double)(B_ROWS * D_DIM));
    float q_lat = (float)(sums[1] / (double)(B_ROWS * D_DIM));
    float vq = q_lat + 0.25f * e_lat;   // fl(q + fl(0.25*e)); 0.25*e exact
    out_scalars[0] = vq;
    out_scalars[1] = e_lat;
    out_scalars[2] = q_lat;
    out_scalars[3] = expf(-(float)tot);
  }
}

extern "C" void kernel_launch(void* const* d_in, const int* in_sizes, int n_in,
                              void* d_out, int out_size, void* d_ws, size_t ws_size,
                              hipStream_t stream) {
  const float* x = (const float*)d_in[0];
  const float* emb = (const float*)d_in[1];
  float* out = (float*)d_out;

  // ws (~420 KB): counts u32[4096] @0 | sums f64[2] @16384 | e2 @16400 |
  //               x2 @32784 | RMMg @163856 | cntg @294928
  unsigned int* counts = (unsigned int*)d_ws;
  double* sums = (double*)((char*)d_ws + 16384);
  float* e2 = (float*)((char*)d_ws + 16400);
  float* x2 = (float*)((char*)d_ws + 32784);
  unsigned int* RMMg = (unsigned int*)((char*)d_ws + 163856);
  unsigned int* cntg = (unsigned int*)((char*)d_ws + 294928);

  // scratch in d_out's quantized region (consumed before vq_gather overwrites):
  // eb u16 @0 (1 MB) | lists u16[32768*64] @1 MB (4 MB) | tvals f32 @5 MB (8 MB)
  unsigned short* eb = (unsigned short*)out;
  unsigned short* listsg = (unsigned short*)((char*)out + (1 << 20));
  float* tvalsg = (float*)((char*)out + (5u << 20));

  float* out_idx = out + (size_t)B_ROWS * D_DIM;
  float* out_scalars = out_idx + B_ROWS;

  hipMemsetAsync(d_ws, 0, 16400, stream);  // zero counts + sums
  prep<<<1024, 256, 0, stream>>>(x, emb, x2, e2, eb);
  sweep<<<B_ROWS / 32, 256, 0, stream>>>(x, eb, e2, RMMg, cntg, listsg, tvalsg);
  rescore<<<B_ROWS / 32, 256, 0, stream>>>(x, emb, x2, e2, RMMg, cntg, listsg,
                                           tvalsg, out_idx, counts);
  vq_gather<<<B_ROWS / 8, 256, 0, stream>>>(x, emb, out_idx, out, sums);
  vq_final<<<1, 256, 0, stream>>>(counts, sums, out_scalars);
}

// Round 10
// 703.539 us; speedup vs baseline: 1.0201x; 1.0201x over previous
//
#include <hip/hip_runtime.h>
#include <math.h>

#define B_ROWS 32768
#define K_CODES 4096
#define D_DIM 128
#define MARGIN 1.5e-3f
#define CAP 64

typedef short bf16x8 __attribute__((ext_vector_type(8)));
typedef float f32x4 __attribute__((ext_vector_type(4)));

// RNE float->bf16 (finite inputs only)
__device__ __forceinline__ unsigned short f2bf(float f) {
  union { float f; unsigned int u; } v; v.f = f;
  unsigned int r = (v.u + 0x7FFFu + ((v.u >> 16) & 1u)) >> 16;
  return (unsigned short)r;
}

// order-preserving float<->uint mapping
__device__ __forceinline__ unsigned fmap(float f) {
  unsigned u = __float_as_uint(f);
  return (u & 0x80000000u) ? ~u : (u | 0x80000000u);
}
__device__ __forceinline__ float funmap(unsigned k) {
  unsigned u = (k & 0x80000000u) ? (k ^ 0x80000000u) : ~k;
  return __uint_as_float(u);
}

// Row sum-of-squares, numpy pairwise order (validated): loads batched FIRST,
// then the asm-guarded VALU chain on registers.  8 lanes/row.
__device__ __forceinline__ float row_sq8(const float* __restrict__ src, int lane) {
  float vals[16];
#pragma unroll
  for (int i = 0; i < 16; ++i) vals[i] = src[i * 8 + lane];  // batched loads
  float t = vals[0] * vals[0];
  asm volatile("" : "+v"(t));  // keep fl(v*v) un-fused (VALU-only barrier)
  float acc = t;
#pragma unroll
  for (int i = 1; i < 16; ++i) {
    float tt = vals[i] * vals[i];
    asm volatile("" : "+v"(tt));
    acc = acc + tt;
  }
  acc = acc + __shfl_xor(acc, 1, 64);
  acc = acc + __shfl_xor(acc, 2, 64);
  acc = acc + __shfl_xor(acc, 4, 64);
  return acc;
}

// ---------------------------------------------------------------------------
// Kernel 1 (round-9 validated): prep — x2, e2, eb bf16 cast packed in
// MFMA-fragment order: eb[((ch*8+nt)*4+ks)*64 + lane]*8 shorts.
// ---------------------------------------------------------------------------
__global__ __launch_bounds__(256) void prep(const float* __restrict__ x,
                                            const float* __restrict__ emb,
                                            float* __restrict__ x2,
                                            float* __restrict__ e2,
                                            unsigned short* __restrict__ eb) {
  const int t0 = blockIdx.x * 256 + threadIdx.x;
  const int stride = gridDim.x * 256;
  for (int s = t0; s < B_ROWS * 8; s += stride) {
    int row = s >> 3, lane = s & 7;
    float acc = row_sq8(x + (size_t)row * D_DIM, lane);
    if (lane == 0) x2[row] = acc;
  }
  for (int s = t0; s < K_CODES * 8; s += stride) {
    int row = s >> 3, lane = s & 7;
    float acc = row_sq8(emb + (size_t)row * D_DIM, lane);
    if (lane == 0) e2[row] = acc;
  }
  for (int g = t0; g < K_CODES * 4; g += stride) {
    int c = g >> 2, ks = g & 3;
    int ch = c >> 7, nt = (c >> 4) & 7, lr = c & 15;
    const float4* src = (const float4*)(emb + (size_t)c * D_DIM + ks * 32);
    unsigned short* dst = eb + ((size_t)((ch * 8 + nt) * 4 + ks) * 64 + lr) * 8;
#pragma unroll
    for (int qq = 0; qq < 4; ++qq) {
      float4 v0 = src[qq * 2];
      float4 v1 = src[qq * 2 + 1];
      ushort4 o0 = make_ushort4(f2bf(v0.x), f2bf(v0.y), f2bf(v0.z), f2bf(v0.w));
      ushort4 o1 = make_ushort4(f2bf(v1.x), f2bf(v1.y), f2bf(v1.z), f2bf(v1.w));
      *(ushort4*)(dst + qq * 128) = o0;
      *(ushort4*)(dst + qq * 128 + 4) = o1;
    }
  }
}

// ---------------------------------------------------------------------------
// Kernel 2 (round-9 validated, unchanged): sweep — single MFMA pass with
// running-bound candidate collection.  256 thr, 32 rows/block, 1024 blocks.
// ---------------------------------------------------------------------------
__global__ __launch_bounds__(256, 3) void sweep(
    const float* __restrict__ x, const unsigned short* __restrict__ eb,
    const float* __restrict__ e2g, unsigned int* __restrict__ RMMg,
    unsigned int* __restrict__ cntg, unsigned short* __restrict__ listsg,
    float* __restrict__ tvalsg) {
  __shared__ float m2[32 * 4];
  __shared__ unsigned RMM[32];
  __shared__ unsigned cnt[32];
  __shared__ unsigned short lists[32 * CAP];
  __shared__ float tvals[32 * CAP];

  const int tid = threadIdx.x;
  const int wid = tid >> 6, lane = tid & 63;
  const int q = lane >> 4, lr = lane & 15;
  const int rowbase = blockIdx.x * 32;

  bf16x8 af[2][4];
#pragma unroll
  for (int mi = 0; mi < 2; ++mi) {
    const float* xr = x + (size_t)(rowbase + mi * 16 + lr) * D_DIM;
#pragma unroll
    for (int ks = 0; ks < 4; ++ks) {
      float4 v0 = *(const float4*)(xr + ks * 32 + q * 8);
      float4 v1 = *(const float4*)(xr + ks * 32 + q * 8 + 4);
      bf16x8 f;
      f[0] = (short)f2bf(v0.x); f[1] = (short)f2bf(v0.y);
      f[2] = (short)f2bf(v0.z); f[3] = (short)f2bf(v0.w);
      f[4] = (short)f2bf(v1.x); f[5] = (short)f2bf(v1.y);
      f[6] = (short)f2bf(v1.z); f[7] = (short)f2bf(v1.w);
      af[mi][ks] = f;
    }
  }
  if (tid < 32) cnt[tid] = 0;

  // ---- chunk 0: calibrate per-row bound ----
  float t0v[2][2][4];
  {
    bf16x8 bf[2][4];
    float ev[2];
#pragma unroll
    for (int ni = 0; ni < 2; ++ni) {
      int nt = wid * 2 + ni;
#pragma unroll
      for (int ks = 0; ks < 4; ++ks)
        bf[ni][ks] = *(const bf16x8*)(eb + ((size_t)(nt * 4 + ks) * 64 + lane) * 8);
      ev[ni] = e2g[nt * 16 + lr];
    }
    f32x4 acc[2][2];
#pragma unroll
    for (int mi = 0; mi < 2; ++mi)
#pragma unroll
      for (int ni = 0; ni < 2; ++ni) { f32x4 z = {0.f, 0.f, 0.f, 0.f}; acc[mi][ni] = z; }
#pragma unroll
    for (int ks = 0; ks < 4; ++ks)
#pragma unroll
      for (int mi = 0; mi < 2; ++mi)
#pragma unroll
        for (int ni = 0; ni < 2; ++ni)
          acc[mi][ni] = __builtin_amdgcn_mfma_f32_16x16x32_bf16(
              af[mi][ks], bf[ni][ks], acc[mi][ni], 0, 0, 0);
#pragma unroll
    for (int mi = 0; mi < 2; ++mi)
#pragma unroll
      for (int ni = 0; ni < 2; ++ni)
#pragma unroll
        for (int rg = 0; rg < 4; ++rg)
          t0v[mi][ni][rg] = __builtin_fmaf(-2.0f, acc[mi][ni][rg], ev[ni]);
  }
#pragma unroll
  for (int sl = 0; sl < 8; ++sl) {
    int mi = sl >> 2, rg = sl & 3;
    float v = fminf(t0v[mi][0][rg], t0v[mi][1][rg]);
    v = fminf(v, __shfl_xor(v, 1, 64));
    v = fminf(v, __shfl_xor(v, 2, 64));
    v = fminf(v, __shfl_xor(v, 4, 64));
    v = fminf(v, __shfl_xor(v, 8, 64));
    if (lr == 0) m2[(mi * 16 + q * 4 + rg) * 4 + wid] = v;
  }
  __syncthreads();
  if (tid < 32) {
    float a = fminf(m2[tid * 4], m2[tid * 4 + 1]);
    float b = fminf(m2[tid * 4 + 2], m2[tid * 4 + 3]);
    RMM[tid] = fmap(fminf(a, b));
  }
  __syncthreads();

  float rm[8];
#pragma unroll
  for (int sl = 0; sl < 8; ++sl)
    rm[sl] = funmap(RMM[(sl >> 2) * 16 + q * 4 + (sl & 3)]);

#pragma unroll
  for (int mi = 0; mi < 2; ++mi)
#pragma unroll
    for (int ni = 0; ni < 2; ++ni) {
      int colc = (wid * 2 + ni) * 16 + lr;
#pragma unroll
      for (int rg = 0; rg < 4; ++rg) {
        float t = t0v[mi][ni][rg];
        if (t <= rm[mi * 4 + rg] + MARGIN) {
          int row = mi * 16 + q * 4 + rg;
          unsigned p = atomicAdd(&cnt[row], 1u);
          if (p < CAP) { lists[row * CAP + p] = (unsigned short)colc; tvals[row * CAP + p] = t; }
        }
      }
    }

#pragma unroll 1
  for (int ch = 1; ch < 32; ++ch) {
    bf16x8 bf[2][4];
    float ev[2];
#pragma unroll
    for (int ni = 0; ni < 2; ++ni) {
      int nt = wid * 2 + ni;
#pragma unroll
      for (int ks = 0; ks < 4; ++ks)
        bf[ni][ks] = *(const bf16x8*)(eb + ((size_t)((ch * 8 + nt) * 4 + ks) * 64 + lane) * 8);
      ev[ni] = e2g[ch * 128 + nt * 16 + lr];
    }
    f32x4 acc[2][2];
#pragma unroll
    for (int mi = 0; mi < 2; ++mi)
#pragma unroll
      for (int ni = 0; ni < 2; ++ni) { f32x4 z = {0.f, 0.f, 0.f, 0.f}; acc[mi][ni] = z; }
#pragma unroll
    for (int ks = 0; ks < 4; ++ks)
#pragma unroll
      for (int mi = 0; mi < 2; ++mi)
#pragma unroll
        for (int ni = 0; ni < 2; ++ni)
          acc[mi][ni] = __builtin_amdgcn_mfma_f32_16x16x32_bf16(
              af[mi][ks], bf[ni][ks], acc[mi][ni], 0, 0, 0);
#pragma unroll
    for (int mi = 0; mi < 2; ++mi)
#pragma unroll
      for (int ni = 0; ni < 2; ++ni) {
        int colc = ch * 128 + (wid * 2 + ni) * 16 + lr;
#pragma unroll
        for (int rg = 0; rg < 4; ++rg) {
          float t = __builtin_fmaf(-2.0f, acc[mi][ni][rg], ev[ni]);
          int sl = mi * 4 + rg;
          if (t <= rm[sl] + MARGIN) {
            int row = mi * 16 + q * 4 + rg;
            unsigned p = atomicAdd(&cnt[row], 1u);
            if (p < CAP) { lists[row * CAP + p] = (unsigned short)colc; tvals[row * CAP + p] = t; }
          }
          rm[sl] = fminf(rm[sl], t);
        }
      }
    if ((ch & 3) == 3) {
#pragma unroll
      for (int sl = 0; sl < 8; ++sl) {
        float v = rm[sl];
        v = fminf(v, __shfl_xor(v, 1, 64));
        v = fminf(v, __shfl_xor(v, 2, 64));
        v = fminf(v, __shfl_xor(v, 4, 64));
        v = fminf(v, __shfl_xor(v, 8, 64));
        rm[sl] = v;
      }
      if (lr == 0) {
#pragma unroll
        for (int sl = 0; sl < 8; ++sl)
          atomicMin(&RMM[(sl >> 2) * 16 + q * 4 + (sl & 3)], fmap(rm[sl]));
      }
#pragma unroll
      for (int sl = 0; sl < 8; ++sl)
        rm[sl] = fminf(rm[sl], funmap(RMM[(sl >> 2) * 16 + q * 4 + (sl & 3)]));
    }
  }
  __syncthreads();

  if (tid < 32) {
    RMMg[rowbase + tid] = RMM[tid];
    cntg[rowbase + tid] = cnt[tid];
  }
  for (int i = tid; i < 32 * CAP; i += 256) {
    listsg[(size_t)rowbase * CAP + i] = lists[i];
    tvalsg[(size_t)rowbase * CAP + i] = tvals[i];
  }
}

// ---------------------------------------------------------------------------
// Kernel 3: rescore v4 — ONE WAVE PER ROW.  4 waves/block, 8192 blocks.
// Lane l handles candidates l and l+64: all pointer-chases concurrent,
// coalesced list/tval reads, filter by final-min+M, exact fp32 chain
// (bit-validated), 6-step shfl-xor lexicographic (s,col) reduction.
// Overflow rows (c > CAP, ~never): the owning wave full-scans 4096 codes
// (64/lane) exactly.  No LDS, no __syncthreads -> no block serialization.
// ---------------------------------------------------------------------------
__global__ __launch_bounds__(256) void rescore(
    const float* __restrict__ x, const float* __restrict__ emb,
    const float* __restrict__ x2g, const float* __restrict__ e2g,
    const unsigned int* __restrict__ RMMg, const unsigned int* __restrict__ cntg,
    const unsigned short* __restrict__ listsg, const float* __restrict__ tvalsg,
    float* __restrict__ out_idx, unsigned int* __restrict__ counts) {
  const int tid = threadIdx.x;
  const int wv = tid >> 6;     // wave in block
  const int lane = tid & 63;
  const int r = blockIdx.x * 4 + wv;

  const float* xr = x + (size_t)r * D_DIM;
  const float xs2 = x2g[r];
  const int c = (int)cntg[r];

  float best = 3.4e38f;
  int bidx = 0x7fffffff;

  if (c <= CAP) {
    const float mlim = funmap(RMMg[r]) + MARGIN;
#pragma unroll
    for (int half = 0; half < 2; ++half) {   // candidates lane, lane+64 (CAP=64 -> half 1 unused, kept for CAP>64 safety)
      int jj = half * 64 + lane;
      if (jj >= c) break;
      float tv = tvalsg[(size_t)r * CAP + jj];
      if (tv > mlim) continue;               // final-min filter
      int col = listsg[(size_t)r * CAP + jj];
      float dot = 0.f;
      const float4* ev = (const float4*)(emb + (size_t)col * D_DIM);
#pragma unroll 8
      for (int d4 = 0; d4 < 32; ++d4) {      // exact ascending-d fmaf chain
        float4 e4 = ev[d4];
        dot = __builtin_fmaf(xr[d4 * 4 + 0], e4.x, dot);
        dot = __builtin_fmaf(xr[d4 * 4 + 1], e4.y, dot);
        dot = __builtin_fmaf(xr[d4 * 4 + 2], e4.z, dot);
        dot = __builtin_fmaf(xr[d4 * 4 + 3], e4.w, dot);
      }
      float t1 = xs2 + e2g[col];                 // fl(x2+e2)
      float s = __builtin_fmaf(-2.0f, dot, t1);  // fl(t1 - 2*dot)
      if (s < best || (s == best && col < bidx)) { best = s; bidx = col; }
    }
  } else {
    // overflow: exact full scan, 64 codes per lane (expected never)
    for (int c0 = lane; c0 < K_CODES; c0 += 64) {
      float dot = 0.f;
      const float4* ev = (const float4*)(emb + (size_t)c0 * D_DIM);
#pragma unroll 8
      for (int d4 = 0; d4 < 32; ++d4) {
        float4 e4 = ev[d4];
        dot = __builtin_fmaf(xr[d4 * 4 + 0], e4.x, dot);
        dot = __builtin_fmaf(xr[d4 * 4 + 1], e4.y, dot);
        dot = __builtin_fmaf(xr[d4 * 4 + 2], e4.z, dot);
        dot = __builtin_fmaf(xr[d4 * 4 + 3], e4.w, dot);
      }
      float s = __builtin_fmaf(-2.0f, dot, xs2 + e2g[c0]);
      if (s < best || (s == best && c0 < bidx)) { best = s; bidx = c0; }
    }
  }

  // 64-lane lexicographic (s, col) min
#pragma unroll
  for (int m = 1; m <= 32; m <<= 1) {
    float ov = __shfl_xor(best, m, 64);
    int oi = __shfl_xor(bidx, m, 64);
    if (ov < best || (ov == best && oi < bidx)) { best = ov; bidx = oi; }
  }
  if (lane == 0) {
    out_idx[r] = (float)bidx;
    atomicAdd(&counts[bidx], 1u);
  }
}

// ---------------------------------------------------------------------------
// Kernel 4 (round-2..9 validated): gather + straight-through + losses.
// ---------------------------------------------------------------------------
__global__ __launch_bounds__(256) void vq_gather(const float* __restrict__ x,
                                                 const float* __restrict__ emb,
                                                 const float* __restrict__ idxf,
                                                 float* __restrict__ out_q,
                                                 double* __restrict__ sums) {
  int r = blockIdx.x * 8 + (threadIdx.x >> 5);
  int lane = threadIdx.x & 31;
  int idx = (int)idxf[r];
  const float4 q = *(const float4*)(emb + (size_t)idx * 128 + lane * 4);
  const float4 xv = *(const float4*)(x + (size_t)r * 128 + lane * 4);
  float d0 = q.x - xv.x, d1 = q.y - xv.y, d2 = q.z - xv.z, d3 = q.w - xv.w;
  float s0 = xv.x + d0, s1 = xv.y + d1, s2 = xv.z + d2, s3 = xv.w + d3;
  *(float4*)(out_q + (size_t)r * 128 + lane * 4) = make_float4(s0, s1, s2, s3);
  float g0 = s0 - xv.x, g1 = s1 - xv.y, g2 = s2 - xv.z, g3 = s3 - xv.w;
  double es = (double)(d0 * d0) + (double)(d1 * d1) + (double)(d2 * d2) + (double)(d3 * d3);
  double qs = (double)(g0 * g0) + (double)(g1 * g1) + (double)(g2 * g2) + (double)(g3 * g3);
#pragma unroll
  for (int off = 32; off >= 1; off >>= 1) {
    es += __shfl_down(es, off, 64);
    qs += __shfl_down(qs, off, 64);
  }
  __shared__ double lred[2][4];
  int w = threadIdx.x >> 6;
  if ((threadIdx.x & 63) == 0) { lred[0][w] = es; lred[1][w] = qs; }
  __syncthreads();
  if (threadIdx.x == 0) {
    double e = lred[0][0] + lred[0][1] + lred[0][2] + lred[0][3];
    double qq = lred[1][0] + lred[1][1] + lred[1][2] + lred[1][3];
    atomicAdd(&sums[0], e);
    atomicAdd(&sums[1], qq);
  }
}

// ---------------------------------------------------------------------------
// Kernel 5 (validated): finalize scalars.
// ---------------------------------------------------------------------------
__global__ __launch_bounds__(256) void vq_final(const unsigned int* __restrict__ counts,
                                                const double* __restrict__ sums,
                                                float* __restrict__ out_scalars) {
  double s = 0.0;
  for (int k = threadIdx.x; k < K_CODES; k += 256) {
    float p = (float)counts[k] * (1.0f / 32768.0f);
    float term = p * logf(p + 1e-10f);
    s += (double)term;
  }
#pragma unroll
  for (int off = 32; off >= 1; off >>= 1) s += __shfl_down(s, off, 64);
  __shared__ double red[4];
  if ((threadIdx.x & 63) == 0) red[threadIdx.x >> 6] = s;
  __syncthreads();
  if (threadIdx.x == 0) {
    double tot = red[0] + red[1] + red[2] + red[3];
    float e_lat = (float)(sums[0] / (double)(B_ROWS * D_DIM));
    float q_lat = (float)(sums[1] / (double)(B_ROWS * D_DIM));
    float vq = q_lat + 0.25f * e_lat;   // fl(q + fl(0.25*e)); 0.25*e exact
    out_scalars[0] = vq;
    out_scalars[1] = e_lat;
    out_scalars[2] = q_lat;
    out_scalars[3] = expf(-(float)tot);
  }
}

extern "C" void kernel_launch(void* const* d_in, const int* in_sizes, int n_in,
                              void* d_out, int out_size, void* d_ws, size_t ws_size,
                              hipStream_t stream) {
  const float* x = (const float*)d_in[0];
  const float* emb = (const float*)d_in[1];
  float* out = (float*)d_out;

  // ws (~420 KB): counts u32[4096] @0 | sums f64[2] @16384 | e2 @16400 |
  //               x2 @32784 | RMMg @163856 | cntg @294928
  unsigned int* counts = (unsigned int*)d_ws;
  double* sums = (double*)((char*)d_ws + 16384);
  float* e2 = (float*)((char*)d_ws + 16400);
  float* x2 = (float*)((char*)d_ws + 32784);
  unsigned int* RMMg = (unsigned int*)((char*)d_ws + 163856);
  unsigned int* cntg = (unsigned int*)((char*)d_ws + 294928);

  // scratch in d_out's quantized region (consumed before vq_gather overwrites):
  // eb u16 @0 (1 MB) | lists u16[32768*64] @1 MB (4 MB) | tvals f32 @5 MB (8 MB)
  unsigned short* eb = (unsigned short*)out;
  unsigned short* listsg = (unsigned short*)((char*)out + (1 << 20));
  float* tvalsg = (float*)((char*)out + (5u << 20));

  float* out_idx = out + (size_t)B_ROWS * D_DIM;
  float* out_scalars = out_idx + B_ROWS;

  hipMemsetAsync(d_ws, 0, 16400, stream);  // zero counts + sums
  prep<<<1024, 256, 0, stream>>>(x, emb, x2, e2, eb);
  sweep<<<B_ROWS / 32, 256, 0, stream>>>(x, eb, e2, RMMg, cntg, listsg, tvalsg);
  rescore<<<B_ROWS / 4, 256, 0, stream>>>(x, emb, x2, e2, RMMg, cntg, listsg,
                                          tvalsg, out_idx, counts);
  vq_gather<<<B_ROWS / 8, 256, 0, stream>>>(x, emb, out_idx, out, sums);
  vq_final<<<1, 256, 0, stream>>>(counts, sums, out_scalars);
}